// Round 13
// baseline (106.896 us; speedup 1.0000x reference)
//
#include <hip/hip_runtime.h>
#include <hip/hip_bf16.h>

typedef __attribute__((ext_vector_type(8))) short bf16x8;
typedef __attribute__((ext_vector_type(4))) float f32x4;

#define CIN   128
#define HW    64
#define OUTC  256

#define BP_OFF     33554432ULL
#define ZP_OFF     34144256ULL
#define WS_NEEDED  34148352ULL

#define SB  __builtin_amdgcn_s_barrier()
#define SCB __builtin_amdgcn_sched_barrier(0)
#define WAITV(N) asm volatile("s_waitcnt vmcnt(" #N ")" ::: "memory")
#define MFMA(a, b, c) __builtin_amdgcn_mfma_f32_16x16x32_bf16(a, b, c, 0, 0, 0)

// ============ fused prep ============
// Xt2: bf16 [32][4][64][64][32]  (b, cc=c>>5, y, x, c&31) — staging-contiguous
// Bp2: bf16 [9][4][256][32]      (ij, cc, n, c&31)
__global__ __launch_bounds__(256) void conv_prep(const float* __restrict__ X,
                                                 const float* __restrict__ Kw,
                                                 __hip_bfloat16* __restrict__ Xt2,
                                                 __hip_bfloat16* __restrict__ Bp2,
                                                 __hip_bfloat16* __restrict__ zp) {
    const int blk = blockIdx.x;
    if (blk < 2048) {
        __shared__ __hip_bfloat16 L[64][136];
        const int b = blk >> 6;
        const int y = blk & 63;
        const int x = threadIdx.x & 63;
        const int c0 = (threadIdx.x >> 6) * 32;
        const float* src = X + (((long)(b * CIN + c0) * HW + y) * HW + x);
        #pragma unroll
        for (int j = 0; j < 32; j += 2) {
            float v0 = src[(long)j * (HW * HW)];
            float v1 = src[(long)(j + 1) * (HW * HW)];
            __hip_bfloat162 p;
            p.x = __float2bfloat16(v0);
            p.y = __float2bfloat16(v1);
            *reinterpret_cast<__hip_bfloat162*>(&L[x][c0 + j]) = p;
        }
        __syncthreads();
        const int xx = threadIdx.x >> 2;
        const int g  = threadIdx.x & 3;
        #pragma unroll
        for (int cc = 0; cc < 4; ++cc) {
            bf16x8 v = *reinterpret_cast<const bf16x8*>(&L[xx][cc * 32 + g * 8]);
            long dst = (((long)(b * 4 + cc) * 64 + y) * 64 + xx) * 32 + g * 8;
            *reinterpret_cast<bf16x8*>(&Xt2[dst]) = v;
        }
    } else if (blk < 2112) {
        for (int i = (blk - 2048) * 256 + threadIdx.x; i < 294912; i += 64 * 256) {
            int c32 = i & 31;
            int n   = (i >> 5) & 255;
            int cc  = (i >> 13) & 3;
            int ij  = i >> 15;
            int c   = cc * 32 + c32;
            Bp2[i] = __float2bfloat16(Kw[(c * 9 + ij) * 256 + n]);
        }
    } else {
        *reinterpret_cast<float4*>((char*)zp + threadIdx.x * 16) = float4{0.f, 0.f, 0.f, 0.f};
    }
}

// ================= implicit GEMM: ring-3, ONE barrier/phase, 2 blocks/CU =================
// M=131072, N=256, K=1152 = 36 halves of 32 (half H: ij=H>>2, cc=H&3)
// BM=128 (2 y-rows), BN=256, 4 waves 1Mx4N, per-wave 128x64
// LDS ring-3: As[3][128*32] (24 KB) + Bs[3][256*32] (48 KB) = 72 KiB -> 2 blocks/CU
// Phase H: [WAITV(6); SB; 12 ds_read(slot H%3); stage(H+2 -> slot (H+2)%3); 32 MFMA]
// Race-freedom (single barrier): slot (H+2)%3 was last READ at phase H-1; every
//   wave's MFMA(H-1) consumed those reads (compiler lgkm waits) BEFORE reaching
//   SB(H); any wave's stage(H+2) is issued AFTER SB(H) => write-after-read safe.
// vmcnt ledger: 6 loads/stage; outstanding<=12 at WAITV; WAITV(6) => stage(H)
//   landed (stage(H+1) may remain in flight); tail 6 -> 0.
__global__ __launch_bounds__(256, 2) void conv_igemm12(
    const __hip_bfloat16* __restrict__ Xt2,
    const __hip_bfloat16* __restrict__ Bp2,
    const __hip_bfloat16* __restrict__ zp,
    float* __restrict__ out)
{
    __shared__ __hip_bfloat16 As[3][128 * 32];
    __shared__ __hip_bfloat16 Bs[3][256 * 32];

    const int tid  = threadIdx.x;
    const int wv   = tid >> 6;       // n-quadrant 0..3
    const int lane = tid & 63;
    const int l16  = lane & 15;
    const int d16  = lane >> 4;

    // XCD-chunked bijective swizzle (1024 % 8 == 0)
    const int bid   = blockIdx.x;
    const int mtile = (bid & 7) * 128 + (bid >> 3);   // 0..1023
    const int b  = mtile >> 5;
    const int y0 = (mtile & 31) * 2;

    const int srow = lane >> 2;      // 0..15
    const int sg   = lane & 3;       // LDS granule slot 0..3

    f32x4 acc[8][4] = {};

    // staging granule: uniform per load (16-row steps are 0 mod 4 after >>1)
    const int G = (sg - (srow >> 1)) & 3;

    // A: rows r = wv*32 + l*16 + srow (l=0,1) of the 128-row tile
    const int rA0 = wv * 32 + srow;
    const int rA1 = rA0 + 16;
    const int xA0 = rA0 & 63, xA1 = rA1 & 63;
    const int yA0 = y0 + (rA0 >> 6), yA1 = y0 + (rA1 >> 6);
    const __hip_bfloat16* pA0 = Xt2 + (((long)b * 16384 + yA0 * 64 + xA0) * 32 + G * 8);
    const __hip_bfloat16* pA1 = Xt2 + (((long)b * 16384 + yA1 * 64 + xA1) * 32 + G * 8);
    const __hip_bfloat16* zpg = zp + G * 8;
    // B: rows r = wv*64 + l*16 + srow (l=0..3)
    const int rB0 = wv * 64 + srow;
    const __hip_bfloat16* pB = Bp2 + ((long)rB0 * 32 + G * 8);
    const int ldsA0 = (wv * 32) * 32;          // bf16 elements
    const int ldsA1 = (wv * 32 + 16) * 32;
    const int ldsB0 = (wv * 64) * 32;

    // stage half S: ij=S>>2, cc=S&3, ring slot S%3. 2 A-loads + 4 B-loads per wave.
    auto stage = [&](int S) {
        const int ij = S >> 2;
        const int cc = S & 3;
        const int di = ij / 3 - 1;
        const int dj = ij % 3 - 1;
        const int rs = S % 3;                  // literal after unroll
        const long offA = ((long)cc * 4096 + di * 64 + dj) * 32;
        const bool ok0 = ((unsigned)(xA0 + dj) < 64u) && ((unsigned)(yA0 + di) < 64u);
        const bool ok1 = ((unsigned)(xA1 + dj) < 64u) && ((unsigned)(yA1 + di) < 64u);
        const __hip_bfloat16* gA0 = ok0 ? pA0 + offA : zpg;
        const __hip_bfloat16* gA1 = ok1 ? pA1 + offA : zpg;
        __hip_bfloat16* ldsA = &As[rs][0];
        __builtin_amdgcn_global_load_lds(
            (const __attribute__((address_space(1))) void*)gA0,
            (__attribute__((address_space(3))) void*)(ldsA + ldsA0), 16, 0, 0);
        __builtin_amdgcn_global_load_lds(
            (const __attribute__((address_space(1))) void*)gA1,
            (__attribute__((address_space(3))) void*)(ldsA + ldsA1), 16, 0, 0);
        const long offB = (long)(ij * 4 + cc) * 8192;
        __hip_bfloat16* ldsB = &Bs[rs][0];
        #pragma unroll
        for (int l = 0; l < 4; ++l) {
            __builtin_amdgcn_global_load_lds(
                (const __attribute__((address_space(1))) void*)(pB + offB + l * 512),
                (__attribute__((address_space(3))) void*)(ldsB + ldsB0 + l * 512), 16, 0, 0);
        }
    };

    // prologue: stage halves 0,1 -> outstanding 12
    stage(0); stage(1);

    #pragma unroll
    for (int H = 0; H < 36; ++H) {
        const int RB = H % 3;
        // ---- wait: my stage(H) landed (stage(H+1)'s 6 may remain in flight) ----
        if (H < 35) WAITV(6); else WAITV(0);
        SCB; SB; SCB;
        // ---- 12 ds_read_b128 from slot H%3 ----
        bf16x8 Af[8], Bf[4];
        #pragma unroll
        for (int mi = 0; mi < 8; ++mi) {
            const int m = mi * 16 + l16;
            const int s = (d16 + (m >> 1)) & 3;
            Af[mi] = *reinterpret_cast<const bf16x8*>(&As[RB][m * 32 + s * 8]);
        }
        #pragma unroll
        for (int ni = 0; ni < 4; ++ni) {
            const int n = wv * 64 + ni * 16 + l16;
            const int s = (d16 + (n >> 1)) & 3;
            Bf[ni] = *reinterpret_cast<const bf16x8*>(&Bs[RB][n * 32 + s * 8]);
        }
        // ---- stage half H+2 into slot (H+2)%3 (readers finished at phase H-1) ----
        if (H < 34) stage(H + 2);
        // ---- 32 MFMA (compiler inserts fine-grained lgkm waits for Af/Bf) ----
        __builtin_amdgcn_s_setprio(1);
        #pragma unroll
        for (int ni = 0; ni < 4; ++ni)
            #pragma unroll
            for (int mi = 0; mi < 8; ++mi)
                acc[mi][ni] = MFMA(Af[mi], Bf[ni], acc[mi][ni]);
        __builtin_amdgcn_s_setprio(0);
    }

    // ---- epilogue: float4 stores; zero y==63 / x==63 ----
    #pragma unroll
    for (int mi = 0; mi < 8; ++mi) {
        const int m  = mi * 16 + d16 * 4;
        const int x0 = m & 63;
        const int y  = y0 + (m >> 6);
        #pragma unroll
        for (int ni = 0; ni < 4; ++ni) {
            const int o = wv * 64 + ni * 16 + l16;
            float4 v;
            v.x = acc[mi][ni][0];
            v.y = acc[mi][ni][1];
            v.z = acc[mi][ni][2];
            v.w = acc[mi][ni][3];
            if (y == HW - 1) { v.x = v.y = v.z = v.w = 0.f; }
            if (x0 + 3 == HW - 1) v.w = 0.f;
            *reinterpret_cast<float4*>(
                out + ((long)(b * OUTC + o) * 4096 + y * 64 + x0)) = v;
        }
    }
}

// ================= fallback (round-1 kernel) if ws too small =================
__global__ __launch_bounds__(256) void conv_igemm_bf16(
    const float* __restrict__ X, const float* __restrict__ Kw, float* __restrict__ out) {
    __shared__ __hip_bfloat16 As[128][40];
    __shared__ __hip_bfloat16 Bs[128][40];
    const int tid = threadIdx.x, wave = tid >> 6, lane = tid & 63;
    const int l16 = lane & 15, d16 = lane >> 4;
    const int m_base = blockIdx.x * 128;
    const int b = m_base >> 12, y0 = (m_base & 4095) >> 6;
    const int n_base = blockIdx.y * 128;
    const int wm = (wave >> 1) * 64, wn = (wave & 1) * 64;
    f32x4 acc[4][4] = {};
    const int smm = tid & 127, ccb = tid >> 7;
    const int sx = smm & 63, syr = smm >> 6;
    for (int ij = 0; ij < 9; ++ij) {
        const int di = ij / 3 - 1, dj = ij % 3 - 1;
        const int xp = sx + dj, yp = y0 + syr + di;
        const bool ok = ((unsigned)xp < 64u) && ((unsigned)yp < 64u);
        const long xbase = (((long)b * CIN) * HW + yp) * HW + xp;
        for (int c0 = 0; c0 < CIN; c0 += 32) {
            for (int cc = ccb; cc < 32; cc += 2) {
                float v = ok ? X[xbase + (long)(c0 + cc) * 4096] : 0.f;
                As[smm][cc] = __float2bfloat16(v);
                Bs[smm][cc] = __float2bfloat16(Kw[((c0 + cc) * 9 + ij) * OUTC + n_base + smm]);
            }
            __syncthreads();
            bf16x8 afrag[4], bfrag[4];
            for (int mi = 0; mi < 4; ++mi)
                afrag[mi] = *reinterpret_cast<const bf16x8*>(&As[wm + mi * 16 + l16][d16 * 8]);
            for (int ni = 0; ni < 4; ++ni)
                bfrag[ni] = *reinterpret_cast<const bf16x8*>(&Bs[wn + ni * 16 + l16][d16 * 8]);
            for (int mi = 0; mi < 4; ++mi)
                for (int ni = 0; ni < 4; ++ni)
                    acc[mi][ni] = __builtin_amdgcn_mfma_f32_16x16x32_bf16(
                        afrag[mi], bfrag[ni], acc[mi][ni], 0, 0, 0);
            __syncthreads();
        }
    }
    for (int mi = 0; mi < 4; ++mi)
        for (int ni = 0; ni < 4; ++ni)
            for (int r = 0; r < 4; ++r) {
                const int mm = wm + mi * 16 + d16 * 4 + r;
                const int nn = wn + ni * 16 + l16;
                const int y = y0 + (mm >> 6), x = mm & 63, o = n_base + nn;
                float v = acc[mi][ni][r];
                if (y == 63 || x == 63) v = 0.f;
                out[(((long)b * OUTC + o) * HW + y) * HW + x] = v;
            }
}

extern "C" void kernel_launch(void* const* d_in, const int* in_sizes, int n_in,
                              void* d_out, int out_size, void* d_ws, size_t ws_size,
                              hipStream_t stream) {
    const float* X  = (const float*)d_in[0];
    const float* Kw = (const float*)d_in[1];
    float* out = (float*)d_out;

    if (ws_size >= WS_NEEDED) {
        char* ws = (char*)d_ws;
        __hip_bfloat16* Xt2 = (__hip_bfloat16*)ws;
        __hip_bfloat16* Bp2 = (__hip_bfloat16*)(ws + BP_OFF);
        __hip_bfloat16* zp  = (__hip_bfloat16*)(ws + ZP_OFF);
        conv_prep<<<dim3(2113), dim3(256), 0, stream>>>(X, Kw, Xt2, Bp2, zp);
        conv_igemm12<<<dim3(1024), dim3(256), 0, stream>>>(Xt2, Bp2, zp, out);
    } else {
        conv_igemm_bf16<<<dim3(1024, 2), dim3(256), 0, stream>>>(X, Kw, out);
    }
}

// Round 14
// 99.342 us; speedup vs baseline: 1.0760x; 1.0760x over previous
//
#include <hip/hip_runtime.h>
#include <hip/hip_bf16.h>

typedef __attribute__((ext_vector_type(8))) short bf16x8;
typedef __attribute__((ext_vector_type(4))) float f32x4;

#define CIN   128
#define HW    64
#define OUTC  256

#define BP_OFF     33554432ULL
#define ZP_OFF     34144256ULL
#define WS_NEEDED  34148352ULL

#define SB  __builtin_amdgcn_s_barrier()
#define SCB __builtin_amdgcn_sched_barrier(0)
#define WAITV(N) asm volatile("s_waitcnt vmcnt(" #N ")" ::: "memory")
#define WAITL    asm volatile("s_waitcnt lgkmcnt(0)" ::: "memory")
#define MFMA(a, b, c) __builtin_amdgcn_mfma_f32_16x16x32_bf16(a, b, c, 0, 0, 0)

// ============ fused prep ============
// Xt2: bf16 [32][4][64][64][32]  (b, cc=c>>5, y, x, c&31) — staging-contiguous
// Bp2: bf16 [9][4][256][32]      (ij, cc, n, c&31)
__global__ __launch_bounds__(256) void conv_prep(const float* __restrict__ X,
                                                 const float* __restrict__ Kw,
                                                 __hip_bfloat16* __restrict__ Xt2,
                                                 __hip_bfloat16* __restrict__ Bp2,
                                                 __hip_bfloat16* __restrict__ zp) {
    const int blk = blockIdx.x;
    if (blk < 2048) {
        __shared__ __hip_bfloat16 L[64][136];
        const int b = blk >> 6;
        const int y = blk & 63;
        const int x = threadIdx.x & 63;
        const int c0 = (threadIdx.x >> 6) * 32;
        const float* src = X + (((long)(b * CIN + c0) * HW + y) * HW + x);
        #pragma unroll
        for (int j = 0; j < 32; j += 2) {
            float v0 = src[(long)j * (HW * HW)];
            float v1 = src[(long)(j + 1) * (HW * HW)];
            __hip_bfloat162 p;
            p.x = __float2bfloat16(v0);
            p.y = __float2bfloat16(v1);
            *reinterpret_cast<__hip_bfloat162*>(&L[x][c0 + j]) = p;
        }
        __syncthreads();
        const int xx = threadIdx.x >> 2;
        const int g  = threadIdx.x & 3;
        #pragma unroll
        for (int cc = 0; cc < 4; ++cc) {
            bf16x8 v = *reinterpret_cast<const bf16x8*>(&L[xx][cc * 32 + g * 8]);
            long dst = (((long)(b * 4 + cc) * 64 + y) * 64 + xx) * 32 + g * 8;
            *reinterpret_cast<bf16x8*>(&Xt2[dst]) = v;
        }
    } else if (blk < 2112) {
        for (int i = (blk - 2048) * 256 + threadIdx.x; i < 294912; i += 64 * 256) {
            int c32 = i & 31;
            int n   = (i >> 5) & 255;
            int cc  = (i >> 13) & 3;
            int ij  = i >> 15;
            int c   = cc * 32 + c32;
            Bp2[i] = __float2bfloat16(Kw[(c * 9 + ij) * 256 + n]);
        }
    } else {
        *reinterpret_cast<float4*>((char*)zp + threadIdx.x * 16) = float4{0.f, 0.f, 0.f, 0.f};
    }
}

// ================= implicit GEMM: race-free dbuf-2, 2 blocks/CU (best: R12) ========
// M=131072, N=256, K=1152 = 36 halves of 32 (half H: ij=H>>2, cc=H&3)
// BM=128 (2 y-rows), BN=256, 4 waves 1Mx4N, per-wave 128x64
// LDS: dbuf-2: As[2][128*32] (16 KB) + Bs[2][256*32] (32 KB) = 48 KiB
// __launch_bounds__(256,2): VGPR 100, no spill ((256,3) caps at 84 -> acc spills)
// Phase H: [WAITV(6); SB; 12 ds_read; WAITL; SB; stage(H+2); 32 MFMA]
// Ledger: prologue 12 outstanding; WAITV(6) at top => stage(H) landed;
//         WAITL+SB before stage(H+2) => no read/write race on buf[H&1].
// Two barriers measured FASTER than one (R13: merging regions -> LDS/vmem contention).
__global__ __launch_bounds__(256, 2) void conv_igemm11(
    const __hip_bfloat16* __restrict__ Xt2,
    const __hip_bfloat16* __restrict__ Bp2,
    const __hip_bfloat16* __restrict__ zp,
    float* __restrict__ out)
{
    __shared__ __hip_bfloat16 As[2][128 * 32];
    __shared__ __hip_bfloat16 Bs[2][256 * 32];

    const int tid  = threadIdx.x;
    const int wv   = tid >> 6;       // n-quadrant 0..3
    const int lane = tid & 63;
    const int l16  = lane & 15;
    const int d16  = lane >> 4;

    // XCD-chunked bijective swizzle (1024 % 8 == 0)
    const int bid   = blockIdx.x;
    const int mtile = (bid & 7) * 128 + (bid >> 3);   // 0..1023
    const int b  = mtile >> 5;
    const int y0 = (mtile & 31) * 2;

    const int srow = lane >> 2;      // 0..15
    const int sg   = lane & 3;       // LDS granule slot 0..3

    f32x4 acc[8][4] = {};

    // staging granule: uniform per load (16-row steps are 0 mod 4 after >>1)
    const int G = (sg - (srow >> 1)) & 3;

    // A: rows r = wv*32 + l*16 + srow (l=0,1) of the 128-row tile
    const int rA0 = wv * 32 + srow;
    const int rA1 = rA0 + 16;
    const int xA0 = rA0 & 63, xA1 = rA1 & 63;
    const int yA0 = y0 + (rA0 >> 6), yA1 = y0 + (rA1 >> 6);
    const __hip_bfloat16* pA0 = Xt2 + (((long)b * 16384 + yA0 * 64 + xA0) * 32 + G * 8);
    const __hip_bfloat16* pA1 = Xt2 + (((long)b * 16384 + yA1 * 64 + xA1) * 32 + G * 8);
    const __hip_bfloat16* zpg = zp + G * 8;
    // B: rows r = wv*64 + l*16 + srow (l=0..3)
    const int rB0 = wv * 64 + srow;
    const __hip_bfloat16* pB = Bp2 + ((long)rB0 * 32 + G * 8);
    const int ldsA0 = (wv * 32) * 32;          // bf16 elements
    const int ldsA1 = (wv * 32 + 16) * 32;
    const int ldsB0 = (wv * 64) * 32;

    // stage half S: ij=S>>2, cc=S&3, dbuf slot S&1. 2 A-loads + 4 B-loads per wave.
    auto stage = [&](int S) {
        const int ij = S >> 2;
        const int cc = S & 3;
        const int di = ij / 3 - 1;
        const int dj = ij % 3 - 1;
        const int rs = S & 1;
        const long offA = ((long)cc * 4096 + di * 64 + dj) * 32;
        const bool ok0 = ((unsigned)(xA0 + dj) < 64u) && ((unsigned)(yA0 + di) < 64u);
        const bool ok1 = ((unsigned)(xA1 + dj) < 64u) && ((unsigned)(yA1 + di) < 64u);
        const __hip_bfloat16* gA0 = ok0 ? pA0 + offA : zpg;
        const __hip_bfloat16* gA1 = ok1 ? pA1 + offA : zpg;
        __hip_bfloat16* ldsA = &As[rs][0];
        __builtin_amdgcn_global_load_lds(
            (const __attribute__((address_space(1))) void*)gA0,
            (__attribute__((address_space(3))) void*)(ldsA + ldsA0), 16, 0, 0);
        __builtin_amdgcn_global_load_lds(
            (const __attribute__((address_space(1))) void*)gA1,
            (__attribute__((address_space(3))) void*)(ldsA + ldsA1), 16, 0, 0);
        const long offB = (long)(ij * 4 + cc) * 8192;
        __hip_bfloat16* ldsB = &Bs[rs][0];
        #pragma unroll
        for (int l = 0; l < 4; ++l) {
            __builtin_amdgcn_global_load_lds(
                (const __attribute__((address_space(1))) void*)(pB + offB + l * 512),
                (__attribute__((address_space(3))) void*)(ldsB + ldsB0 + l * 512), 16, 0, 0);
        }
    };

    // prologue: stage halves 0,1 -> outstanding 12
    stage(0); stage(1);

    #pragma unroll
    for (int H = 0; H < 36; ++H) {
        const int RB = H & 1;
        // ---- wait: my stage(H) landed (stage(H+1)'s 6 may remain in flight) ----
        if (H < 35) WAITV(6); else WAITV(0);
        SCB; SB;
        // ---- 12 ds_read_b128 ----
        bf16x8 Af[8], Bf[4];
        #pragma unroll
        for (int mi = 0; mi < 8; ++mi) {
            const int m = mi * 16 + l16;
            const int s = (d16 + (m >> 1)) & 3;
            Af[mi] = *reinterpret_cast<const bf16x8*>(&As[RB][m * 32 + s * 8]);
        }
        #pragma unroll
        for (int ni = 0; ni < 4; ++ni) {
            const int n = wv * 64 + ni * 16 + l16;
            const int s = (d16 + (n >> 1)) & 3;
            Bf[ni] = *reinterpret_cast<const bf16x8*>(&Bs[RB][n * 32 + s * 8]);
        }
        WAITL;          // reads drained before anyone may overwrite this buffer
        SCB; SB;
        // ---- stage half H+2 into the buffer just consumed ----
        if (H < 34) stage(H + 2);
        // ---- 32 MFMA ----
        __builtin_amdgcn_s_setprio(1);
        #pragma unroll
        for (int ni = 0; ni < 4; ++ni)
            #pragma unroll
            for (int mi = 0; mi < 8; ++mi)
                acc[mi][ni] = MFMA(Af[mi], Bf[ni], acc[mi][ni]);
        __builtin_amdgcn_s_setprio(0);
    }

    // ---- epilogue: float4 stores; zero y==63 / x==63 ----
    #pragma unroll
    for (int mi = 0; mi < 8; ++mi) {
        const int m  = mi * 16 + d16 * 4;
        const int x0 = m & 63;
        const int y  = y0 + (m >> 6);
        #pragma unroll
        for (int ni = 0; ni < 4; ++ni) {
            const int o = wv * 64 + ni * 16 + l16;
            float4 v;
            v.x = acc[mi][ni][0];
            v.y = acc[mi][ni][1];
            v.z = acc[mi][ni][2];
            v.w = acc[mi][ni][3];
            if (y == HW - 1) { v.x = v.y = v.z = v.w = 0.f; }
            if (x0 + 3 == HW - 1) v.w = 0.f;
            *reinterpret_cast<float4*>(
                out + ((long)(b * OUTC + o) * 4096 + y * 64 + x0)) = v;
        }
    }
}

// ================= fallback (round-1 kernel) if ws too small =================
__global__ __launch_bounds__(256) void conv_igemm_bf16(
    const float* __restrict__ X, const float* __restrict__ Kw, float* __restrict__ out) {
    __shared__ __hip_bfloat16 As[128][40];
    __shared__ __hip_bfloat16 Bs[128][40];
    const int tid = threadIdx.x, wave = tid >> 6, lane = tid & 63;
    const int l16 = lane & 15, d16 = lane >> 4;
    const int m_base = blockIdx.x * 128;
    const int b = m_base >> 12, y0 = (m_base & 4095) >> 6;
    const int n_base = blockIdx.y * 128;
    const int wm = (wave >> 1) * 64, wn = (wave & 1) * 64;
    f32x4 acc[4][4] = {};
    const int smm = tid & 127, ccb = tid >> 7;
    const int sx = smm & 63, syr = smm >> 6;
    for (int ij = 0; ij < 9; ++ij) {
        const int di = ij / 3 - 1, dj = ij % 3 - 1;
        const int xp = sx + dj, yp = y0 + syr + di;
        const bool ok = ((unsigned)xp < 64u) && ((unsigned)yp < 64u);
        const long xbase = (((long)b * CIN) * HW + yp) * HW + xp;
        for (int c0 = 0; c0 < CIN; c0 += 32) {
            for (int cc = ccb; cc < 32; cc += 2) {
                float v = ok ? X[xbase + (long)(c0 + cc) * 4096] : 0.f;
                As[smm][cc] = __float2bfloat16(v);
                Bs[smm][cc] = __float2bfloat16(Kw[((c0 + cc) * 9 + ij) * OUTC + n_base + smm]);
            }
            __syncthreads();
            bf16x8 afrag[4], bfrag[4];
            for (int mi = 0; mi < 4; ++mi)
                afrag[mi] = *reinterpret_cast<const bf16x8*>(&As[wm + mi * 16 + l16][d16 * 8]);
            for (int ni = 0; ni < 4; ++ni)
                bfrag[ni] = *reinterpret_cast<const bf16x8*>(&Bs[wn + ni * 16 + l16][d16 * 8]);
            for (int mi = 0; mi < 4; ++mi)
                for (int ni = 0; ni < 4; ++ni)
                    acc[mi][ni] = __builtin_amdgcn_mfma_f32_16x16x32_bf16(
                        afrag[mi], bfrag[ni], acc[mi][ni], 0, 0, 0);
            __syncthreads();
        }
    }
    for (int mi = 0; mi < 4; ++mi)
        for (int ni = 0; ni < 4; ++ni)
            for (int r = 0; r < 4; ++r) {
                const int mm = wm + mi * 16 + d16 * 4 + r;
                const int nn = wn + ni * 16 + l16;
                const int y = y0 + (mm >> 6), x = mm & 63, o = n_base + nn;
                float v = acc[mi][ni][r];
                if (y == 63 || x == 63) v = 0.f;
                out[(((long)b * OUTC + o) * HW + y) * HW + x] = v;
            }
}

extern "C" void kernel_launch(void* const* d_in, const int* in_sizes, int n_in,
                              void* d_out, int out_size, void* d_ws, size_t ws_size,
                              hipStream_t stream) {
    const float* X  = (const float*)d_in[0];
    const float* Kw = (const float*)d_in[1];
    float* out = (float*)d_out;

    if (ws_size >= WS_NEEDED) {
        char* ws = (char*)d_ws;
        __hip_bfloat16* Xt2 = (__hip_bfloat16*)ws;
        __hip_bfloat16* Bp2 = (__hip_bfloat16*)(ws + BP_OFF);
        __hip_bfloat16* zp  = (__hip_bfloat16*)(ws + ZP_OFF);
        conv_prep<<<dim3(2113), dim3(256), 0, stream>>>(X, Kw, Xt2, Bp2, zp);
        conv_igemm11<<<dim3(1024), dim3(256), 0, stream>>>(Xt2, Bp2, zp, out);
    } else {
        conv_igemm_bf16<<<dim3(1024, 2), dim3(256), 0, stream>>>(X, Kw, out);
    }
}